// Round 1
// baseline (1134.161 us; speedup 1.0000x reference)
//
#include <hip/hip_runtime.h>
#include <cstddef>
#include <cstdint>

#define N_NODES 50000
#define N_EDGES 800000
#define F_IN 50
#define K1PAD 64
#define H_DIM 512
#define O_DIM 121
#define N_GROUPS 20
#define EPSV 1e-5f
#define M_PAD 50176      // 196 * 256 = 392 * 128
#define M_TILES 392      // 128-row tiles (layer-1 kernel)
#define M_TILES256 196   // 256-row tiles (8-phase kernel)

#define SCAN_BLK 256
#define SCAN_NBLK ((N_NODES + SCAN_BLK - 1) / SCAN_BLK)  // 196
#define WALL_EL 1769472
#define XB_EL (M_PAD * K1PAD)

typedef unsigned short u16;
typedef __attribute__((ext_vector_type(8))) short short8;          // 8 bf16 (4 VGPRs)
typedef __attribute__((ext_vector_type(8))) unsigned short u16x8;  // 16B vector load
typedef __attribute__((ext_vector_type(4))) float f32x4;

__device__ __forceinline__ float b2f(u16 u) {
  union { unsigned int i; float f; } v; v.i = ((unsigned int)u) << 16; return v.f;
}
__device__ __forceinline__ u16 f2b(float f) {
  union { float f; unsigned int i; } v; v.f = f;
  unsigned int x = v.i;
  return (u16)((x + 0x7fffu + ((x >> 16) & 1u)) >> 16);  // RNE
}

__device__ __forceinline__ void gl_lds16(const void* g, void* l) {
  __builtin_amdgcn_global_load_lds(
      (__attribute__((address_space(1))) void*)(g),
      (__attribute__((address_space(3))) void*)(l), 16, 0, 0);
}

// ---------------- graph preprocessing ----------------

__global__ void k_deg(const int* __restrict__ dst, int* __restrict__ deg) {
  int e = blockIdx.x * blockDim.x + threadIdx.x;
  if (e < N_EDGES) atomicAdd(&deg[dst[e]], 1);
}

__global__ void k_scan1(const int* __restrict__ deg, int* __restrict__ off,
                        int* __restrict__ bsum) {
  __shared__ int buf[SCAN_BLK];
  int gid = blockIdx.x * SCAN_BLK + threadIdx.x;
  buf[threadIdx.x] = (gid < N_NODES) ? deg[gid] : 0;
  __syncthreads();
  for (int d = 1; d < SCAN_BLK; d <<= 1) {
    int t = (threadIdx.x >= d) ? buf[threadIdx.x - d] : 0;
    __syncthreads();
    buf[threadIdx.x] += t;
    __syncthreads();
  }
  if (gid < N_NODES) off[gid + 1] = buf[threadIdx.x];
  if (threadIdx.x == SCAN_BLK - 1) bsum[blockIdx.x] = buf[threadIdx.x];
}

// block 0: scan of block sums; block 1: group bounds from sorted batch
__global__ void k_scan2_gbounds(int* __restrict__ bsum, const int* __restrict__ batch,
                                int* __restrict__ gstart, float* __restrict__ inv_sz) {
  int t = threadIdx.x;
  if (blockIdx.x == 0) {
    __shared__ int buf[256];
    buf[t] = (t < SCAN_NBLK) ? bsum[t] : 0;
    __syncthreads();
    for (int d = 1; d < 256; d <<= 1) {
      int v = (t >= d) ? buf[t - d] : 0;
      __syncthreads();
      buf[t] += v;
      __syncthreads();
    }
    if (t < SCAN_NBLK) bsum[t] = buf[t];
  } else {
    if (t <= N_GROUPS) {
      int lo = 0, hi = N_NODES;
      while (lo < hi) {
        int mid = (lo + hi) >> 1;
        if (batch[mid] < t) lo = mid + 1; else hi = mid;
      }
      gstart[t] = lo;
    }
    __syncthreads();
    if (t < N_GROUPS) {
      int sz = gstart[t + 1] - gstart[t];
      inv_sz[t] = 1.0f / (float)max(sz, 1);
    }
  }
}

__global__ void k_scan3prep(int* __restrict__ off, const int* __restrict__ bsum,
                            const int* __restrict__ deg, float* __restrict__ inv_deg,
                            int* __restrict__ cursor) {
  int gid = blockIdx.x * SCAN_BLK + threadIdx.x;
  if (gid < N_NODES) {
    int add = (blockIdx.x > 0) ? bsum[blockIdx.x - 1] : 0;
    int v = off[gid + 1] + add;
    off[gid + 1] = v;
    if (gid + 1 < N_NODES) cursor[gid + 1] = v;
    inv_deg[gid] = 1.0f / (float)max(deg[gid], 1);
  }
  if (gid == 0) { off[0] = 0; cursor[0] = 0; }
}

__global__ void k_scatter(const int* __restrict__ src, const int* __restrict__ dst,
                          int* __restrict__ cursor, int* __restrict__ csr_src) {
  int e = blockIdx.x * blockDim.x + threadIdx.x;
  if (e < N_EDGES) {
    int p = atomicAdd(&cursor[dst[e]], 1);
    csr_src[p] = src[e];
  }
}

// ---------------- conversions (x pad + all weights, one launch) -------------
struct WcSrc { const float* p[10]; };
__global__ void k_convert_all(const float* __restrict__ x, WcSrc s,
                              u16* __restrict__ xb, u16* __restrict__ wall) {
  int idx = blockIdx.x * blockDim.x + threadIdx.x;
  if (idx < XB_EL) {
    int r = idx >> 6, c = idx & (K1PAD - 1);
    float v = (r < N_NODES && c < F_IN) ? x[r * F_IN + c] : 0.f;
    xb[idx] = f2b(v);
    return;
  }
  idx -= XB_EL;
  if (idx >= WALL_EL) return;
  const int seg_start[10] = {0, 32768, 65536, 327680, 589824, 851968,
                             1114112, 1376256, 1638400, 1703936};
  const int jr[10]  = {512, 512, 512, 512, 512, 512, 512, 512, 121, 121};
  const int kin[10] = {50, 50, 512, 512, 512, 512, 512, 512, 512, 512};
  const int ksh[10] = {6, 6, 9, 9, 9, 9, 9, 9, 9, 9};
  int sgi = 0;
#pragma unroll
  for (int t = 1; t < 10; ++t)
    if (idx >= seg_start[t]) sgi = t;
  int local = idx - seg_start[sgi];
  int j = local >> ksh[sgi];
  int k = local & ((1 << ksh[sgi]) - 1);
  float v = (j < jr[sgi] && k < kin[sgi]) ? s.p[sgi][j * kin[sgi] + k] : 0.f;
  wall[idx] = f2b(v);
}

// ---------------- aggregation ----------------

__global__ void k_agg_small(const u16* __restrict__ xb, const int* __restrict__ off,
                            const int* __restrict__ srcs, const float* __restrict__ inv_deg,
                            u16* __restrict__ agg) {
  int n = blockIdx.x;
  int f = threadIdx.x;  // 0..63
  int b = off[n], e = off[n + 1];
  float s = 0.f;
  for (int i = b; i < e; ++i) s += b2f(xb[(size_t)srcs[i] * K1PAD + f]);
  agg[(size_t)n * K1PAD + f] = f2b(s * inv_deg[n]);
}

// layers 2..4: 16B loads, 2 waves per node (edge split), 4 nodes per block.
// ~111 us: pinned at the L2-miss/L3 path ceiling for the random row gather
// (374 MB fetch of 819 MB logical) — occupancy/unroll variants all neutral.
__global__ __launch_bounds__(512) void k_agg512(
    const u16* __restrict__ h, const int* __restrict__ off,
    const int* __restrict__ srcs, const float* __restrict__ inv_deg,
    u16* __restrict__ agg) {
  __shared__ float part[4][64][8];  // 8 KB
  int slot = threadIdx.y >> 1;
  int sub = threadIdx.y & 1;
  int n = blockIdx.x * 4 + slot;
  int t = threadIdx.x;
  float a[8] = {0.f, 0.f, 0.f, 0.f, 0.f, 0.f, 0.f, 0.f};
  if (n < N_NODES) {
    int b = off[n], e = off[n + 1];
    int half = (e - b + 1) >> 1;
    int lo = b + sub * half;
    int hi = min(lo + half, e);
    int i = lo;
    for (; i + 4 <= hi; i += 4) {
      u16x8 v0 = ((const u16x8*)(h + (size_t)srcs[i + 0] * H_DIM))[t];
      u16x8 v1 = ((const u16x8*)(h + (size_t)srcs[i + 1] * H_DIM))[t];
      u16x8 v2 = ((const u16x8*)(h + (size_t)srcs[i + 2] * H_DIM))[t];
      u16x8 v3 = ((const u16x8*)(h + (size_t)srcs[i + 3] * H_DIM))[t];
#pragma unroll
      for (int j = 0; j < 8; ++j)
        a[j] += (b2f(v0[j]) + b2f(v1[j])) + (b2f(v2[j]) + b2f(v3[j]));
    }
    for (; i < hi; ++i) {
      u16x8 v0 = ((const u16x8*)(h + (size_t)srcs[i] * H_DIM))[t];
#pragma unroll
      for (int j = 0; j < 8; ++j) a[j] += b2f(v0[j]);
    }
  }
  if (sub == 1) {
#pragma unroll
    for (int j = 0; j < 8; ++j) part[slot][t][j] = a[j];
  }
  __syncthreads();
  if (sub == 0 && n < N_NODES) {
    float w = inv_deg[n];
    u16x8 r;
#pragma unroll
    for (int j = 0; j < 8; ++j) r[j] = f2b((a[j] + part[slot][t][j]) * w);
    ((u16x8*)(agg + (size_t)n * H_DIM))[t] = r;
  }
}

// layer 5 final: out[n] = inv_deg[n]*sum(Pl[src]) + Pr[n] + bias (121 cols)
__global__ __launch_bounds__(256) void k_agg_final(
    const u16* __restrict__ Plb, const float* __restrict__ Prf,
    const int* __restrict__ off, const int* __restrict__ srcs,
    const float* __restrict__ inv_deg, const float* __restrict__ bias,
    float* __restrict__ out) {
  int n = blockIdx.x * 8 + (threadIdx.x >> 5);
  if (n >= N_NODES) return;
  int l = threadIdx.x & 31;
  int c0 = l * 4;
  int b = off[n], e = off[n + 1];
  float a0 = 0.f, a1 = 0.f, a2 = 0.f, a3 = 0.f;
  int i = b;
  for (; i + 2 <= e; i += 2) {
    ushort4 v0 = ((const ushort4*)(Plb + (size_t)srcs[i] * 128))[l];
    ushort4 v1 = ((const ushort4*)(Plb + (size_t)srcs[i + 1] * 128))[l];
    a0 += b2f(v0.x) + b2f(v1.x); a1 += b2f(v0.y) + b2f(v1.y);
    a2 += b2f(v0.z) + b2f(v1.z); a3 += b2f(v0.w) + b2f(v1.w);
  }
  if (i < e) {
    ushort4 v0 = ((const ushort4*)(Plb + (size_t)srcs[i] * 128))[l];
    a0 += b2f(v0.x); a1 += b2f(v0.y); a2 += b2f(v0.z); a3 += b2f(v0.w);
  }
  float w = inv_deg[n];
  float4 pr = ((const float4*)(Prf + (size_t)n * 128))[l];
  float r0 = a0 * w + pr.x, r1 = a1 * w + pr.y;
  float r2 = a2 * w + pr.z, r3 = a3 * w + pr.w;
  size_t ob = (size_t)n * O_DIM;
  if (c0 + 0 < O_DIM) out[ob + c0 + 0] = r0 + bias[c0 + 0];
  if (c0 + 1 < O_DIM) out[ob + c0 + 1] = r1 + bias[c0 + 1];
  if (c0 + 2 < O_DIM) out[ob + c0 + 2] = r2 + bias[c0 + 2];
  if (c0 + 3 < O_DIM) out[ob + c0 + 3] = r3 + bias[c0 + 3];
}

// ---------------- MFMA GEMM (layer 1 only: K=64 dual) ----------------

#define TM 128
#define TK 32

template <int JB, bool DUAL, int OUTMODE>
__global__ __launch_bounds__(256, 4) void k_gemm_mfma(
    const u16* __restrict__ A, const u16* __restrict__ X,
    const u16* __restrict__ Wl, const u16* __restrict__ Wr,
    const float* __restrict__ bias, void* __restrict__ C0,
    void* __restrict__ C1, const int* __restrict__ batch,
    float* __restrict__ ssum, float* __restrict__ ssq, int K) {
  __shared__ u16 As[TM * TK];
  __shared__ u16 Ls[TM * TK];
  __shared__ u16 Xs[DUAL ? TM * TK : 1];
  __shared__ u16 Rs[DUAL ? TM * TK : 1];

  int id = blockIdx.x;
  const int nfull = (M_TILES >> 3) * 8 * JB;
  int m_t, j_t;
  if (id < nfull) {
    m_t = (id / (8 * JB)) * 8 + (id & 7);
    j_t = (id >> 3) & (JB - 1);
  } else {
    int rem = id - nfull;
    const int nrem = M_TILES & 7;
    m_t = (M_TILES & ~7) + rem % nrem;
    j_t = rem / nrem;
  }
  int m0 = m_t * TM;
  int j0 = j_t * 128;

  int tid = threadIdx.x;
  int lane = tid & 63;
  int wave = tid >> 6;
  int quad = lane >> 4;
  int lr = lane & 15;
  int wm = (wave & 1) * 64;
  int wn = (wave >> 1) * 64;

  f32x4 acc[4][4] = {};

  int sr = tid >> 2;
  int sc = (tid & 3) * 8;
  size_t moff0 = (size_t)(m0 + sr) * K + sc;
  size_t moff1 = moff0 + (size_t)64 * K;
  size_t joff0 = (size_t)(j0 + sr) * K + sc;
  size_t joff1 = joff0 + (size_t)64 * K;
  const int dofs = tid * 8;

  for (int k0 = 0; k0 < K; k0 += TK) {
    __syncthreads();
    gl_lds16(A + moff0 + k0, As + dofs);
    gl_lds16(A + moff1 + k0, As + 2048 + dofs);
    gl_lds16(Wl + joff0 + k0, Ls + dofs);
    gl_lds16(Wl + joff1 + k0, Ls + 2048 + dofs);
    if constexpr (DUAL) {
      gl_lds16(X + moff0 + k0, Xs + dofs);
      gl_lds16(X + moff1 + k0, Xs + 2048 + dofs);
      gl_lds16(Wr + joff0 + k0, Rs + dofs);
      gl_lds16(Wr + joff1 + k0, Rs + 2048 + dofs);
    }
    __syncthreads();
    {
      short8 af[4], lf[4];
#pragma unroll
      for (int t = 0; t < 4; ++t) {
        af[t] = *(const short8*)(As + (wm + t * 16 + lr) * TK + quad * 8);
        lf[t] = *(const short8*)(Ls + (wn + t * 16 + lr) * TK + quad * 8);
      }
#pragma unroll
      for (int ti = 0; ti < 4; ++ti)
#pragma unroll
        for (int tj = 0; tj < 4; ++tj)
          acc[ti][tj] = __builtin_amdgcn_mfma_f32_16x16x32_bf16(
              af[ti], lf[tj], acc[ti][tj], 0, 0, 0);
    }
    if constexpr (DUAL) {
      short8 xf[4], rf[4];
#pragma unroll
      for (int t = 0; t < 4; ++t) {
        xf[t] = *(const short8*)(Xs + (wm + t * 16 + lr) * TK + quad * 8);
        rf[t] = *(const short8*)(Rs + (wn + t * 16 + lr) * TK + quad * 8);
      }
#pragma unroll
      for (int ti = 0; ti < 4; ++ti)
#pragma unroll
        for (int tj = 0; tj < 4; ++tj)
          acc[ti][tj] = __builtin_amdgcn_mfma_f32_16x16x32_bf16(
              xf[ti], rf[tj], acc[ti][tj], 0, 0, 0);
    }
  }

  if constexpr (OUTMODE == 0) {
    int glo = batch[m0];
    int lastrow = m0 + TM - 1;
    bool fast = (lastrow < N_NODES) && (batch[lastrow] == glo);
#pragma unroll
    for (int tj = 0; tj < 4; ++tj) {
      int gcol = j0 + wn + tj * 16 + lr;
      float bv = bias[gcol];
      float s = 0.f, q = 0.f;
#pragma unroll
      for (int ti = 0; ti < 4; ++ti) {
        f32x4 v = acc[ti][tj];
        int rbase = m0 + wm + ti * 16 + quad * 4;
        if (fast) {
#pragma unroll
          for (int r = 0; r < 4; ++r) {
            float val = v[r] + bv;
            ((u16*)C0)[(size_t)(rbase + r) * H_DIM + gcol] = f2b(val);
            s += val; q += val * val;
          }
        } else {
          if (rbase + 3 < N_NODES && batch[rbase] == batch[rbase + 3]) {
            float s4 = 0.f, q4 = 0.f;
#pragma unroll
            for (int r = 0; r < 4; ++r) {
              float val = v[r] + bv;
              ((u16*)C0)[(size_t)(rbase + r) * H_DIM + gcol] = f2b(val);
              s4 += val; q4 += val * val;
            }
            int g = batch[rbase];
            atomicAdd(&ssum[g * H_DIM + gcol], s4);
            atomicAdd(&ssq[g * H_DIM + gcol], q4);
          } else {
#pragma unroll
            for (int r = 0; r < 4; ++r) {
              int grow = rbase + r;
              if (grow < N_NODES) {
                float val = v[r] + bv;
                ((u16*)C0)[(size_t)grow * H_DIM + gcol] = f2b(val);
                int g = batch[grow];
                atomicAdd(&ssum[g * H_DIM + gcol], val);
                atomicAdd(&ssq[g * H_DIM + gcol], val * val);
              }
            }
          }
        }
      }
      if (fast) {
        s += __shfl_xor(s, 16); s += __shfl_xor(s, 32);
        q += __shfl_xor(q, 16); q += __shfl_xor(q, 32);
        if (quad == 0) {
          atomicAdd(&ssum[glo * H_DIM + gcol], s);
          atomicAdd(&ssq[glo * H_DIM + gcol], q);
        }
      }
    }
  } else {
#pragma unroll
    for (int tj = 0; tj < 4; ++tj) {
      int gcol = j0 + wn + tj * 16 + lr;
#pragma unroll
      for (int ti = 0; ti < 4; ++ti) {
        f32x4 v = acc[ti][tj];
#pragma unroll
        for (int r = 0; r < 4; ++r) {
          int grow = m0 + wm + ti * 16 + quad * 4 + r;
          if (gcol < 128)
            ((u16*)C0)[(size_t)grow * 128 + gcol] = f2b(v[r]);
          else
            ((float*)C1)[(size_t)grow * 128 + (gcol - 128)] = v[r];
        }
      }
    }
  }
}

// ---------------- 256x256 8-phase MFMA GEMM (layers 2..5) ----------------
// K-concat dual: tiles 0..7 read (Aa, Bl), tiles 8..15 read (Ax, Br), BK=64.
// Schedule (per K-tile t, 4 phases q0..q3, verified vmcnt/WAR algebra):
//   q0: ds A-band0(8)+B-nj01(4) | stage A1(t+1)   | bar | mfma band0 x nj01 | bar
//   q1: ds B-nj23(4)            | stage A0(t+2)   | bar | mfma band0 x nj23 | bar
//   q2: ds A-band1(8)           | stage B0(t+2)   | bar | mfma band1 x nj01 | bar
//   q3: (regs)                  | stage B1(t+2)   | vmcnt(6) bar | mfma band1 x nj23 | bar
// Stage->read distance is 4..7 phases; vmcnt(6) (3 half-tiles in flight) at q3
// guarantees every chunk before its first read. Drain vmcnt(0) at t==knt-2.
// T2 swizzle: phys 16B slot = logical ^ (row&7), baked into the *global* src of
// global_load_lds (linear LDS dest) and into the ds_read column offset.

template <int OUTMODE>
__global__ __launch_bounds__(512, 2) void k_gemm256(
    const u16* __restrict__ Aa, const u16* __restrict__ Ax,
    const u16* __restrict__ Bl, const u16* __restrict__ Br,
    const float* __restrict__ bias, void* __restrict__ C0,
    void* __restrict__ C1, const int* __restrict__ batch,
    float* __restrict__ ssum, float* __restrict__ ssq, int knt) {
  __shared__ u16 LA[2][256][64];  // 64 KB
  __shared__ u16 LB[2][256][64];  // 64 KB

  int m_t, j_t;
  if constexpr (OUTMODE == 0) {
    // grid == 392 == 8*49: XCD-chunked bijective swizzle; j-pair of one m-tile
    // stays on one XCD (A-panel L2 reuse).
    int lg = (blockIdx.x & 7) * 49 + (blockIdx.x >> 3);
    m_t = lg >> 1; j_t = lg & 1;
  } else {
    m_t = blockIdx.x; j_t = 0;
  }
  const int m0 = m_t << 8;
  const int j0 = j_t << 8;

  const int tid = threadIdx.x;
  const int lane = tid & 63;
  const int wave = tid >> 6;
  const int lr = lane & 15;
  const int quad = lane >> 4;
  const int wr64 = ((wave >> 2) & 1) << 6;  // row offset within band
  const int wc64 = (wave & 3) << 6;         // col offset
  const int rtid = tid >> 3;
  const int sw = ((tid & 7) ^ (rtid & 7)) << 3;           // stage src slot swizzle (u16)
  const int c16_0 = (quad << 3) ^ ((lr & 7) << 3);        // ds_read swz col, ks=0
  const int c16_1 = (32 + (quad << 3)) ^ ((lr & 7) << 3); // ks=1

  f32x4 acc[2][4][4] = {};
  short8 af[4][2];
  short8 bf[4][2];

  auto STAGE = [&](int tt, int kind) {  // kind: 0=A rows0-127,1=A rows128-255,2=B0,3=B1
    if (tt >= knt) return;
    const int bb = tt & 1;
    const int ktl = (tt & 7) << 6;
    if (kind <= 1) {
      const u16* src = (tt >= 8) ? Ax : Aa;
      const int r0 = kind << 7;
      const u16* s0 = src + (size_t)(m0 + r0 + rtid) * 512 + ktl + sw;
      u16* d = &LA[bb][r0][0] + tid * 8;
      gl_lds16(s0, d);
      gl_lds16(s0 + (size_t)64 * 512, d + 4096);
    } else {
      const u16* src = (tt >= 8) ? Br : Bl;
      const int r0 = (kind - 2) << 7;
      const u16* s0 = src + (size_t)(j0 + r0 + rtid) * 512 + ktl + sw;
      u16* d = &LB[bb][r0][0] + tid * 8;
      gl_lds16(s0, d);
      gl_lds16(s0 + (size_t)64 * 512, d + 4096);
    }
  };

  // prologue: tile0 {A0,B0,B1,A1} + tile1 {A0,B0,B1}; A1(1) staged at t0.q0.
  STAGE(0, 0); STAGE(0, 2); STAGE(0, 3); STAGE(0, 1);
  STAGE(1, 0); STAGE(1, 2); STAGE(1, 3);
  asm volatile("s_waitcnt vmcnt(6)" ::: "memory");
  __builtin_amdgcn_s_barrier();

  for (int t = 0; t < knt; ++t) {
    const int b = t & 1;
    const u16* ABase = &LA[b][0][0];
    const u16* BBase = &LB[b][0][0];
    const u16* abr = ABase + (size_t)(wr64 + lr) * 64;
    const u16* bbr = BBase + (size_t)(wc64 + lr) * 64;

    // ---- q0
#pragma unroll
    for (int mi = 0; mi < 4; ++mi) {
      af[mi][0] = *(const short8*)(abr + mi * 1024 + c16_0);
      af[mi][1] = *(const short8*)(abr + mi * 1024 + c16_1);
    }
#pragma unroll
    for (int nj = 0; nj < 2; ++nj) {
      bf[nj][0] = *(const short8*)(bbr + nj * 1024 + c16_0);
      bf[nj][1] = *(const short8*)(bbr + nj * 1024 + c16_1);
    }
    STAGE(t + 1, 1);
    __builtin_amdgcn_s_barrier();
    __builtin_amdgcn_s_setprio(1);
#pragma unroll
    for (int mi = 0; mi < 4; ++mi)
#pragma unroll
      for (int nj = 0; nj < 2; ++nj) {
        acc[0][mi][nj] = __builtin_amdgcn_mfma_f32_16x16x32_bf16(
            af[mi][0], bf[nj][0], acc[0][mi][nj], 0, 0, 0);
        acc[0][mi][nj] = __builtin_amdgcn_mfma_f32_16x16x32_bf16(
            af[mi][1], bf[nj][1], acc[0][mi][nj], 0, 0, 0);
      }
    __builtin_amdgcn_s_setprio(0);
    __builtin_amdgcn_s_barrier();

    // ---- q1
#pragma unroll
    for (int nj = 2; nj < 4; ++nj) {
      bf[nj][0] = *(const short8*)(bbr + nj * 1024 + c16_0);
      bf[nj][1] = *(const short8*)(bbr + nj * 1024 + c16_1);
    }
    STAGE(t + 2, 0);
    __builtin_amdgcn_s_barrier();
    __builtin_amdgcn_s_setprio(1);
#pragma unroll
    for (int mi = 0; mi < 4; ++mi)
#pragma unroll
      for (int nj = 2; nj < 4; ++nj) {
        acc[0][mi][nj] = __builtin_amdgcn_mfma_f32_16x16x32_bf16(
            af[mi][0], bf[nj][0], acc[0][mi][nj], 0, 0, 0);
        acc[0][mi][nj] = __builtin_amdgcn_mfma_f32_16x16x32_bf16(
            af[mi][1], bf[nj][1], acc[0][mi][nj], 0, 0, 0);
      }
    __builtin_amdgcn_s_setprio(0);
    __builtin_amdgcn_s_barrier();

    // ---- q2
#pragma unroll
    for (int mi = 0; mi < 4; ++mi) {
      af[mi][0] = *(const short8*)(abr + 8192 + mi * 1024 + c16_0);
      af[mi][1] = *(const short8*)(abr + 8192 + mi * 1024 + c16_1);
    }
    STAGE(t + 2, 2);
    __builtin_amdgcn_s_barrier();
    __builtin_amdgcn_s_setprio(1);
#pragma unroll
    for (int mi = 0; mi < 4; ++mi)
#pragma unroll
      for (int nj = 0; nj < 2; ++nj) {
        acc[1][mi][nj] = __builtin_amdgcn_mfma_f32_16x16x32_bf16(
            af[mi][0], bf[nj][0], acc[1][mi][nj], 0, 0, 0);
        acc[1][mi][nj] = __builtin_amdgcn_mfma_f32_16x16x32_bf16(
            af[mi][1], bf[nj][1], acc[1][mi][nj], 0, 0, 0);
      }
    __builtin_amdgcn_s_setprio(0);
    __builtin_amdgcn_s_barrier();

    // ---- q3
    STAGE(t + 2, 3);
    if (t < knt - 2) {
      asm volatile("s_waitcnt vmcnt(6)" ::: "memory");
    } else if (t == knt - 2) {
      asm volatile("s_waitcnt vmcnt(0)" ::: "memory");
    }
    __builtin_amdgcn_s_barrier();
    __builtin_amdgcn_s_setprio(1);
#pragma unroll
    for (int mi = 0; mi < 4; ++mi)
#pragma unroll
      for (int nj = 2; nj < 4; ++nj) {
        acc[1][mi][nj] = __builtin_amdgcn_mfma_f32_16x16x32_bf16(
            af[mi][0], bf[nj][0], acc[1][mi][nj], 0, 0, 0);
        acc[1][mi][nj] = __builtin_amdgcn_mfma_f32_16x16x32_bf16(
            af[mi][1], bf[nj][1], acc[1][mi][nj], 0, 0, 0);
      }
    __builtin_amdgcn_s_setprio(0);
    __builtin_amdgcn_s_barrier();
  }

  // epilogue: C/D layout col=lane&15, row=quad*4+reg
  if constexpr (OUTMODE == 0) {
    int glo = batch[m0];
    int lastrow = m0 + 255;
    bool fast = (lastrow < N_NODES) && (batch[lastrow] == glo);
#pragma unroll
    for (int nj = 0; nj < 4; ++nj) {
      int gcol = j0 + wc64 + nj * 16 + lr;
      float bv = bias[gcol];
      float s = 0.f, q = 0.f;
#pragma unroll
      for (int band = 0; band < 2; ++band)
#pragma unroll
        for (int mi = 0; mi < 4; ++mi) {
          f32x4 v = acc[band][mi][nj];
          int rbase = m0 + band * 128 + wr64 + mi * 16 + quad * 4;
          if (fast) {
#pragma unroll
            for (int r = 0; r < 4; ++r) {
              float val = v[r] + bv;
              ((u16*)C0)[(size_t)(rbase + r) * H_DIM + gcol] = f2b(val);
              s += val; q += val * val;
            }
          } else if (rbase + 3 < N_NODES && batch[rbase] == batch[rbase + 3]) {
            float s4 = 0.f, q4 = 0.f;
#pragma unroll
            for (int r = 0; r < 4; ++r) {
              float val = v[r] + bv;
              ((u16*)C0)[(size_t)(rbase + r) * H_DIM + gcol] = f2b(val);
              s4 += val; q4 += val * val;
            }
            int g = batch[rbase];
            atomicAdd(&ssum[g * H_DIM + gcol], s4);
            atomicAdd(&ssq[g * H_DIM + gcol], q4);
          } else {
#pragma unroll
            for (int r = 0; r < 4; ++r) {
              int grow = rbase + r;
              if (grow < N_NODES) {
                float val = v[r] + bv;
                ((u16*)C0)[(size_t)grow * H_DIM + gcol] = f2b(val);
                int g = batch[grow];
                atomicAdd(&ssum[g * H_DIM + gcol], val);
                atomicAdd(&ssq[g * H_DIM + gcol], val * val);
              }
            }
          }
        }
      if (fast) {
        s += __shfl_xor(s, 16); s += __shfl_xor(s, 32);
        q += __shfl_xor(q, 16); q += __shfl_xor(q, 32);
        if (quad == 0) {
          atomicAdd(&ssum[glo * H_DIM + gcol], s);
          atomicAdd(&ssq[glo * H_DIM + gcol], q);
        }
      }
    }
  } else {
#pragma unroll
    for (int nj = 0; nj < 4; ++nj) {
      int gcol = wc64 + nj * 16 + lr;
#pragma unroll
      for (int band = 0; band < 2; ++band)
#pragma unroll
        for (int mi = 0; mi < 4; ++mi) {
          f32x4 v = acc[band][mi][nj];
#pragma unroll
          for (int r = 0; r < 4; ++r) {
            int grow = m0 + band * 128 + wr64 + mi * 16 + quad * 4 + r;
            if (gcol < 128)
              ((u16*)C0)[(size_t)grow * 128 + gcol] = f2b(v[r]);
            else
              ((float*)C1)[(size_t)grow * 128 + (gcol - 128)] = v[r];
          }
        }
    }
  }
}

// ---------------- GraphNorm: precompute affine, then apply+relu -------------

__global__ void k_precomp(const float* __restrict__ ssum, const float* __restrict__ ssq,
                          const float* __restrict__ inv_sz, const float* __restrict__ gw,
                          const float* __restrict__ gb, const float* __restrict__ alpha,
                          float* __restrict__ S, float* __restrict__ T) {
  int idx = blockIdx.x * blockDim.x + threadIdx.x;
  if (idx >= N_GROUPS * H_DIM) return;
  int g = idx >> 9;
  int c = idx & (H_DIM - 1);
  float is = inv_sz[g];
  float m = ssum[idx] * is;
  float a = alpha[c];
  float var = fmaxf(ssq[idx] * is - a * (2.f - a) * m * m, 0.f);
  float inv = rsqrtf(var + EPSV);
  float sc = inv * gw[c];
  S[idx] = sc;
  T[idx] = gb[c] - a * m * sc;
}

__global__ void k_apply(u16* __restrict__ h, const int* __restrict__ batch,
                        const float* __restrict__ S, const float* __restrict__ T) {
  int tid = blockIdx.x * blockDim.x + threadIdx.x;
  if (tid >= N_NODES * (H_DIM / 8)) return;
  int n = tid >> 6;
  int c0 = (tid & 63) << 3;
  int g = batch[n];
  u16x8 hv = *(const u16x8*)(h + (size_t)n * H_DIM + c0);
  u16x8 out;
#pragma unroll
  for (int j = 0; j < 8; ++j) {
    int f = c0 + j;
    float y = b2f(hv[j]) * S[g * H_DIM + f] + T[g * H_DIM + f];
    out[j] = f2b(fmaxf(y, 0.f));
  }
  *(u16x8*)(h + (size_t)n * H_DIM + c0) = out;
}

// ---------------- driver ----------------

extern "C" void kernel_launch(void* const* d_in, const int* in_sizes, int n_in,
                              void* d_out, int out_size, void* d_ws, size_t ws_size,
                              hipStream_t stream) {
  const float* x = (const float*)d_in[0];
  const int* edge = (const int*)d_in[1];
  const int* batch = (const int*)d_in[2];
  const float *Wl[5], *Wr[5], *bb[5];
  for (int i = 0; i < 5; ++i) {
    Wl[i] = (const float*)d_in[3 + 3 * i];
    Wr[i] = (const float*)d_in[4 + 3 * i];
    bb[i] = (const float*)d_in[5 + 3 * i];
  }
  const float *gamma[4], *beta[4], *alpha[4];
  for (int i = 0; i < 4; ++i) {
    gamma[i] = (const float*)d_in[18 + 3 * i];
    beta[i]  = (const float*)d_in[19 + 3 * i];
    alpha[i] = (const float*)d_in[20 + 3 * i];
  }
  const int* srcv = edge;
  const int* dstv = edge + N_EDGES;

  char* base = (char*)d_ws;
  size_t off = 0;
  auto carve = [&](size_t bytes) -> char* {
    char* p = base + off;
    off = (off + bytes + 255) & ~(size_t)255;
    return p;
  };
  int* deg       = (int*)carve((size_t)N_NODES * 4);
  float* inv_deg = (float*)carve((size_t)N_NODES * 4);
  int* csr_off   = (int*)carve((size_t)(N_NODES + 1) * 4);
  int* cursor    = (int*)carve((size_t)N_NODES * 4);
  int* csr_src   = (int*)carve((size_t)N_EDGES * 4);
  int* bsum      = (int*)carve((size_t)SCAN_NBLK * 4);
  int* gstart    = (int*)carve((size_t)(N_GROUPS + 1) * 4);
  float* inv_sz  = (float*)carve((size_t)N_GROUPS * 4);
  float* stats   = (float*)carve((size_t)4 * 2 * N_GROUPS * H_DIM * 4);
  float* Sbuf    = (float*)carve((size_t)N_GROUPS * H_DIM * 4);
  float* Tbuf    = (float*)carve((size_t)N_GROUPS * H_DIM * 4);
  u16* xb        = (u16*)carve((size_t)XB_EL * 2);
  u16* aggx      = (u16*)carve((size_t)XB_EL * 2);
  u16* h0        = (u16*)carve((size_t)M_PAD * H_DIM * 2);
  u16* h1        = (u16*)carve((size_t)M_PAD * H_DIM * 2);
  u16* h2        = (u16*)carve((size_t)M_PAD * H_DIM * 2);
  u16* wall      = (u16*)carve((size_t)WALL_EL * 2);
  (void)ws_size; (void)in_sizes; (void)n_in; (void)out_size;

  u16* w1lb = wall;
  u16* w1rb = wall + 32768;
  u16* w2lb = wall + 65536;
  u16* w2rb = wall + 327680;
  u16* w3lb = wall + 589824;
  u16* w3rb = wall + 851968;
  u16* w4lb = wall + 1114112;
  u16* w4rb = wall + 1376256;
  u16* w5cat = wall + 1638400;  // 256 x 512

  u16* Plb = h1;
  float* Prf = (float*)((char*)h1 + (size_t)M_PAD * 128 * 2);

  // graph preprocessing
  hipMemsetAsync(deg, 0, (size_t)N_NODES * 4, stream);
  k_deg<<<(N_EDGES + 255) / 256, 256, 0, stream>>>(dstv, deg);
  k_scan1<<<SCAN_NBLK, SCAN_BLK, 0, stream>>>(deg, csr_off, bsum);
  k_scan2_gbounds<<<2, 256, 0, stream>>>(bsum, batch, gstart, inv_sz);
  k_scan3prep<<<SCAN_NBLK, SCAN_BLK, 0, stream>>>(csr_off, bsum, deg, inv_deg, cursor);
  k_scatter<<<(N_EDGES + 255) / 256, 256, 0, stream>>>(srcv, dstv, cursor, csr_src);

  WcSrc ws_src;
  ws_src.p[0] = Wl[0]; ws_src.p[1] = Wr[0];
  ws_src.p[2] = Wl[1]; ws_src.p[3] = Wr[1];
  ws_src.p[4] = Wl[2]; ws_src.p[5] = Wr[2];
  ws_src.p[6] = Wl[3]; ws_src.p[7] = Wr[3];
  ws_src.p[8] = Wl[4]; ws_src.p[9] = Wr[4];
  k_convert_all<<<(XB_EL + WALL_EL + 255) / 256, 256, 0, stream>>>(x, ws_src, xb, wall);

  hipMemsetAsync(stats, 0, (size_t)4 * 2 * N_GROUPS * H_DIM * 4, stream);

  const int nblk_l1 = M_TILES * 4;        // 1568 (layer-1 128x128 kernel)
  const int nblk_256 = M_TILES256 * 2;    // 392 (layers 2-4, N=512)
  dim3 aggblk(64, 8);
  int aggrid = (N_NODES + 3) / 4;

  auto norm = [&](u16* h, int l) {
    float* ss = stats + (size_t)l * 2 * N_GROUPS * H_DIM;
    float* sq = ss + N_GROUPS * H_DIM;
    k_precomp<<<(N_GROUPS * H_DIM + 255) / 256, 256, 0, stream>>>(
        ss, sq, inv_sz, gamma[l], beta[l], alpha[l], Sbuf, Tbuf);
    k_apply<<<(N_NODES * (H_DIM / 8) + 255) / 256, 256, 0, stream>>>(
        h, batch, Sbuf, Tbuf);
  };
  auto stat_ptr = [&](int l) { return stats + (size_t)l * 2 * N_GROUPS * H_DIM; };

  // layer 1 (K = 64 padded, small K: keep 128x128 kernel)
  k_agg_small<<<N_NODES, 64, 0, stream>>>(xb, csr_off, csr_src, inv_deg, aggx);
  k_gemm_mfma<4, true, 0><<<nblk_l1, 256, 0, stream>>>(
      aggx, xb, w1lb, w1rb, bb[0], h0, nullptr, batch,
      stat_ptr(0), stat_ptr(0) + N_GROUPS * H_DIM, K1PAD);
  norm(h0, 0);

  // layer 2 (K-concat 1024, 16 K-tiles)
  k_agg512<<<aggrid, aggblk, 0, stream>>>(h0, csr_off, csr_src, inv_deg, h1);
  k_gemm256<0><<<nblk_256, 512, 0, stream>>>(
      h1, h0, w2lb, w2rb, bb[1], h2, nullptr, batch,
      stat_ptr(1), stat_ptr(1) + N_GROUPS * H_DIM, 16);
  norm(h2, 1);

  // layer 3
  k_agg512<<<aggrid, aggblk, 0, stream>>>(h2, csr_off, csr_src, inv_deg, h0);
  k_gemm256<0><<<nblk_256, 512, 0, stream>>>(
      h0, h2, w3lb, w3rb, bb[2], h1, nullptr, batch,
      stat_ptr(2), stat_ptr(2) + N_GROUPS * H_DIM, 16);
  norm(h1, 2);

  // layer 4
  k_agg512<<<aggrid, aggblk, 0, stream>>>(h1, csr_off, csr_src, inv_deg, h2);
  k_gemm256<0><<<nblk_256, 512, 0, stream>>>(
      h2, h1, w4lb, w4rb, bb[3], h0, nullptr, batch,
      stat_ptr(3), stat_ptr(3) + N_GROUPS * H_DIM, 16);
  norm(h0, 3);

  // layer 5 via linearity: P = h0 @ [W5l|W5r]^T (J=256, K=512 -> 8 tiles)
  k_gemm256<1><<<M_TILES256, 512, 0, stream>>>(
      h0, h0, w5cat, w5cat, nullptr, Plb, Prf, nullptr, nullptr, nullptr, 8);
  k_agg_final<<<(N_NODES + 7) / 8, 256, 0, stream>>>(
      Plb, Prf, csr_off, csr_src, inv_deg, bb[4], (float*)d_out);
}